// Round 8
// baseline (183.518 us; speedup 1.0000x reference)
//
#include <hip/hip_runtime.h>
#include <stdint.h>
#include <math.h>

#define NH 16
#define DH 64
#define SEQ 2048
#define DMODEL 1024

typedef short short8 __attribute__((ext_vector_type(8)));
typedef short short4v __attribute__((ext_vector_type(4)));
typedef float f32x4 __attribute__((ext_vector_type(4)));
typedef __bf16 bf16x4 __attribute__((ext_vector_type(4)));

__device__ __forceinline__ short f2bf(float f) {
  __bf16 h = (__bf16)f;
  return __builtin_bit_cast(short, h);
}
__device__ __forceinline__ short4v cvt4(f32x4 v) {
  bf16x4 b = __builtin_convertvector(v, bf16x4);
  return __builtin_bit_cast(short4v, b);
}
__device__ __forceinline__ float fast_exp2(float x) {
#if __has_builtin(__builtin_amdgcn_exp2f)
  return __builtin_amdgcn_exp2f(x);
#else
  return exp2f(x);
#endif
}

typedef const __attribute__((address_space(1))) uint32_t* gp_t;
typedef __attribute__((address_space(3))) uint32_t* lp_t;
__device__ __forceinline__ void async16(const short* g, short* l) {
  __builtin_amdgcn_global_load_lds((gp_t)g, (lp_t)l, 16, 0, 0);
}

// ---- fused prep: x fp32->bf16 | w_in^T bf16 | w_out^T bf16 (one launch) ----
__device__ __forceinline__ void transpose_tile(const float* __restrict__ in,
                                               short* __restrict__ out, int R, int C,
                                               int t, int tilesX, int tid) {
  __shared__ float tile[32][33];
  const int tx = tid & 31, ty = tid >> 5;  // 32 x 8
  const int c0 = (t % tilesX) * 32, r0 = (t / tilesX) * 32;
#pragma unroll
  for (int i = 0; i < 4; ++i)
    tile[ty + i * 8][tx] = in[(size_t)(r0 + ty + i * 8) * C + c0 + tx];
  __syncthreads();
#pragma unroll
  for (int i = 0; i < 4; ++i)
    out[(size_t)(c0 + ty + i * 8) * R + r0 + tx] = f2bf(tile[tx][ty + i * 8]);
}

__global__ void k_prep(const float* __restrict__ x, short* __restrict__ xb,
                       const float* __restrict__ w_in, short* __restrict__ w_in_t,
                       const float* __restrict__ w_out, short* __restrict__ w_out_t) {
  const int tid = threadIdx.x;
  const int blk = blockIdx.x;
  if (blk < 4096) {  // x convert
    const int i = blk * 256 + tid;
    f32x4 v = ((const f32x4*)x)[i];
    ((short4v*)xb)[i] = cvt4(v);
  } else if (blk < 4096 + 3072) {  // w_in [1024,3072] -> [3072,1024]
    transpose_tile(w_in, w_in_t, 1024, 3072, blk - 4096, 96, tid);
  } else {  // w_out [1024,1024] -> transpose
    transpose_tile(w_out, w_out_t, 1024, 1024, blk - 7168, 32, tid);
  }
}

// ---------------- GEMM: C[M,N] = A[M,K=1024] * Bt[N,K]^T + bias ------------
// BK=64: 16 K-iters x 32 MFMA. LDS tiles 128x64, XOR-chunk-swizzled so
// global_load_lds (linear, wave-uniform-base) + conflict-free b128 reads.
template <int MODE>
__launch_bounds__(256, 3)
__global__ void k_gemm(const short* __restrict__ A, const short* __restrict__ Bt,
                       const float* __restrict__ bias, float* __restrict__ Cf,
                       short* __restrict__ qo, short* __restrict__ ko,
                       short* __restrict__ vo) {
  constexpr int KD = 1024;
  __shared__ __align__(16) short As[128 * 64];  // 16 KB
  __shared__ __align__(16) short Bs[128 * 64];  // 16 KB
  const int tid = threadIdx.x;
  const int wave = tid >> 6, lane = tid & 63;
  const int quad = lane >> 4, l16 = lane & 15;
  const int wm = wave >> 1, wn = wave & 1;
  const int tM = blockIdx.y * 128, tN = blockIdx.x * 128;

  const short* pA[4];
  const short* pB[4];
  short* lA[4];
  short* lB[4];
#pragma unroll
  for (int t = 0; t < 4; ++t) {
    const int c = t * 256 + tid;
    const int row = c >> 3, gch = (c & 7) ^ (row & 7);
    pA[t] = A + (size_t)(tM + row) * KD + gch * 8;
    pB[t] = Bt + (size_t)(tN + row) * KD + gch * 8;
    lA[t] = &As[c * 8];
    lB[t] = &Bs[c * 8];
  }

  const int sw = l16 & 7;
  const int col0 = (quad ^ sw) << 3;
  const int col1 = col0 ^ 32;

  f32x4 acc[4][4] = {};

  for (int k0 = 0; k0 < KD; k0 += 64) {
    __syncthreads();
#pragma unroll
    for (int t = 0; t < 4; ++t) {
      async16(pA[t] + k0, lA[t]);
      async16(pB[t] + k0, lB[t]);
    }
    __syncthreads();
#pragma unroll
    for (int kh = 0; kh < 2; ++kh) {
      const int col = kh ? col1 : col0;
      short8 af[4], bfr[4];
#pragma unroll
      for (int i = 0; i < 4; ++i)
        af[i] = *(const short8*)&As[(wm * 64 + i * 16 + l16) * 64 + col];
#pragma unroll
      for (int i = 0; i < 4; ++i)
        bfr[i] = *(const short8*)&Bs[(wn * 64 + i * 16 + l16) * 64 + col];
#pragma unroll
      for (int i = 0; i < 4; ++i)
#pragma unroll
        for (int j = 0; j < 4; ++j)
          acc[i][j] = __builtin_amdgcn_mfma_f32_16x16x32_bf16(af[i], bfr[j], acc[i][j], 0, 0, 0);
    }
  }

  const int rbase = tM + wm * 64 + quad * 4;
#pragma unroll
  for (int i = 0; i < 4; ++i) {
#pragma unroll
    for (int j = 0; j < 4; ++j) {
      const int col = tN + wn * 64 + j * 16 + l16;
      const float bi = bias[col];
      if (MODE == 0) {
        const int which = col >> 10;  // uniform per block
        const int h = (col & 1023) >> 6, d = col & 63;
        if (which == 2) {
          const int row0 = rbase + i * 16;
          const int b = row0 >> 11, li0 = row0 & 2047;
          f32x4 t;
#pragma unroll
          for (int rr = 0; rr < 4; ++rr) t[rr] = acc[i][j][rr] + bi;
          *(short4v*)&vo[(((size_t)(b * NH + h)) * DH + d) * SEQ + li0] = cvt4(t);
        } else {
          short* dst = (which == 0) ? qo : ko;
#pragma unroll
          for (int rr = 0; rr < 4; ++rr) {
            const int row = rbase + i * 16 + rr;
            const int b = row >> 11, li = row & 2047;
            dst[(((size_t)(b * NH + h)) * SEQ + li) * DH + d] = f2bf(acc[i][j][rr] + bi);
          }
        }
      } else {
#pragma unroll
        for (int rr = 0; rr < 4; ++rr) {
          const int row = rbase + i * 16 + rr;
          Cf[(size_t)row * DMODEL + col] = acc[i][j][rr] + bi;
        }
      }
    }
  }
}

// -------- flash attention: key-split waves, LDS traffic halved --------------
// Fixed-FM softmax => key dim is a PURE SUM => waves may partition keys with
// no online-softmax coupling. wave=(qh,kh): 32 q-rows (qh half) x 32 keys
// (kh half) per 64-key tile. K-frag reads 8->4, V 8->4 b128/wave/tile (the
// LDS pipe was ~70% of the kernel; all 4 waves previously read the SAME
// tiles). All MFMA layouts stay 16x16x32. accL via VALU adds + end shuffles.
// T15 carry (PV one tile behind, register-carried pa/va) + staging +
// balanced qt remap + setprio preserved from round 7. End: kh=1 partials
// merged into kh=0 via LDS scratch (reuses Ks/Vs after a barrier).
__launch_bounds__(256)
__global__ void k_attn(const short* __restrict__ q, const short* __restrict__ k,
                       const short* __restrict__ vt, short* __restrict__ o) {
  __shared__ __align__(16) short Ks[2][64 * 64];  // 2 x 8 KB
  __shared__ __align__(16) short Vs[2][64 * 64];  // 2 x 8 KB, V^T tile [d][key]
  __shared__ __align__(16) short Ps[4][16 * 64];  // per-wave P, swizzled
  const int tid = threadIdx.x;
  const int wave = tid >> 6, lane = tid & 63;
  const int quad = lane >> 4, l16 = lane & 15;
  const int sw = l16 & 7;
  const int qh = wave >> 1, kh = wave & 1;
  const int bx = blockIdx.x;
  const int g = bx >> 5, g0 = g & 7, sel = g >> 3;
  const int qt = (sel == 0) ? 31 - g0 : (sel == 1) ? g0 : (sel == 2) ? 23 - g0 : 8 + g0;
  const int bh = bx & 31;
  const int h = bh & (NH - 1);
  const size_t base = (size_t)bh * SEQ * DH;
  const float LOG2E = 1.44269504088896f;
  const float slope2 = exp2f(-0.5f * (float)(h + 1)) * LOG2E;
  const float scale2 = 0.125f * LOG2E;
  const float FM = 12.0f;  // fixed softmax max; cancels in O/l exactly

  // staging chunks: c = t*256+tid, row=c>>3, ch=(c&7)^(row&7); lds off = c*16B
  const int c0i = tid, c1i = 256 + tid;
  const int r0 = c0i >> 3, ch0 = (c0i & 7) ^ (r0 & 7);
  const int r1 = c1i >> 3, ch1 = (c1i & 7) ^ (r1 & 7);
  const int qk_off0 = r0 * DH + ch0 * 8;
  const int qk_off1 = r1 * DH + ch1 * 8;
  const int v_off0 = r0 * SEQ + ch0 * 8;
  const int v_off1 = r1 * SEQ + ch1 * 8;

  const int q0 = qt * 64;
  const int qrowA = q0 + qh * 32 + l16;  // q-block 0 row owned by this lane
  const int qrowB = qrowA + 16;          // q-block 1

  // Q fragments (B-operand): two q-blocks x two 32-d slices
  const short* qpA = q + base + (size_t)qrowA * DH + quad * 8;
  const short* qpB = q + base + (size_t)qrowB * DH + quad * 8;
  const short8 qA0 = *(const short8*)qpA;
  const short8 qA1 = *(const short8*)(qpA + 32);
  const short8 qB0 = *(const short8*)qpB;
  const short8 qB1 = *(const short8*)(qpB + 32);

  // K frag read cols (A-operand, d-chunks quad and quad+4, row-swizzled)
  const int kcol0 = (quad ^ sw) << 3;
  const int kcol1 = kcol0 ^ 32;
  // V frag col: global key-chunk kh*4+quad
  const int vcol = (((kh * 4 + quad) ^ sw) << 3);
  // Ps write: chunk = qb*4 + kb*2 + (quad>>1), off (quad&1)*4
  int pwoff[2][2];
#pragma unroll
  for (int qb = 0; qb < 2; ++qb)
#pragma unroll
    for (int kb = 0; kb < 2; ++kb)
      pwoff[qb][kb] = l16 * 64 + ((((qb * 4 + kb * 2 + (quad >> 1))) ^ sw) << 3) + (quad & 1) * 4;
  // pa read: chunk = qb*4 + quad
  const int proff0 = l16 * 64 + (((0 * 4 + quad) ^ sw) << 3);
  const int proff1 = l16 * 64 + (((1 * 4 + quad) ^ sw) << 3);

  // alibi bias (log2 domain): ioff[qb][kb] + rc[r] + s*scale2
  float ioff[2][2];
#pragma unroll
  for (int qb = 0; qb < 2; ++qb)
#pragma unroll
    for (int kb = 0; kb < 2; ++kb)
      ioff[qb][kb] = -slope2 * (float)(q0 + qh * 32 + qb * 16 + l16) - FM +
                     slope2 * (float)(kh * 32 + kb * 16 + 4 * quad);
  const float s64 = slope2 * 64.0f;
  float rc[4];
#pragma unroll
  for (int r = 0; r < 4; ++r) rc[r] = slope2 * (float)r;
  // causal limits: mask r > lim[qb][kb] on the diagonal tile
  int lim[2][2];
#pragma unroll
  for (int qb = 0; qb < 2; ++qb)
#pragma unroll
    for (int kb = 0; kb < 2; ++kb)
      lim[qb][kb] = (qh - kh) * 32 + 16 * (qb - kb) + l16 - 4 * quad;

  f32x4 accO[4][2] = {};  // [dblk][qb]
  float accLp[2] = {0.f, 0.f};

  const short* kp = k + base;
  const short* vp = vt + base;

  // stage tile 0 into buf 0
  async16(kp + qk_off0, &Ks[0][c0i * 8]);
  async16(kp + qk_off1, &Ks[0][c1i * 8]);
  async16(vp + v_off0, &Vs[0][c0i * 8]);
  async16(vp + v_off1, &Vs[0][c1i * 8]);
  kp += 64 * DH;
  vp += 64;
  __syncthreads();

  // cross-tile carried PV operands
  short8 paA, paB;
  short8 var[4];

  for (int kt = 0; kt <= qt; ++kt) {
    const int cur = kt & 1, nxt = cur ^ 1;
    if (kt < qt) {
      async16(kp + qk_off0, &Ks[nxt][c0i * 8]);
      async16(kp + qk_off1, &Ks[nxt][c1i * 8]);
      async16(vp + v_off0, &Vs[nxt][c0i * 8]);
      async16(vp + v_off1, &Vs[nxt][c1i * 8]);
      kp += 64 * DH;
      vp += 64;
    }

    // S^T = K Q^T over this wave's 32-key half: s[kb][qb]
    f32x4 s[2][2];
    __builtin_amdgcn_s_setprio(1);
#pragma unroll
    for (int kb = 0; kb < 2; ++kb) {
      const int in = 2 * kh + kb;
      const short8 ka0 = *(const short8*)&Ks[cur][(in * 16 + l16) * 64 + kcol0];
      const short8 ka1 = *(const short8*)&Ks[cur][(in * 16 + l16) * 64 + kcol1];
      f32x4 t0 = {};
      t0 = __builtin_amdgcn_mfma_f32_16x16x32_bf16(ka0, qA0, t0, 0, 0, 0);
      t0 = __builtin_amdgcn_mfma_f32_16x16x32_bf16(ka1, qA1, t0, 0, 0, 0);
      s[kb][0] = t0;
      f32x4 t1 = {};
      t1 = __builtin_amdgcn_mfma_f32_16x16x32_bf16(ka0, qB0, t1, 0, 0, 0);
      t1 = __builtin_amdgcn_mfma_f32_16x16x32_bf16(ka1, qB1, t1, 0, 0, 0);
      s[kb][1] = t1;
    }

    // PV(kt-1) from carried registers — independent of the QK->exp chain
    if (kt > 0) {
#pragma unroll
      for (int i = 0; i < 4; ++i) {
        accO[i][0] = __builtin_amdgcn_mfma_f32_16x16x32_bf16(var[i], paA, accO[i][0], 0, 0, 0);
        accO[i][1] = __builtin_amdgcn_mfma_f32_16x16x32_bf16(var[i], paB, accO[i][1], 0, 0, 0);
      }
    }
    __builtin_amdgcn_s_setprio(0);

    // V(kt) fragments -> carried registers (this wave's key half)
#pragma unroll
    for (int i = 0; i < 4; ++i)
      var[i] = *(const short8*)&Vs[cur][(i * 16 + l16) * 64 + vcol];

    // exp + accL partial + Ps write
    if (kt == qt) {
#pragma unroll
      for (int kb = 0; kb < 2; ++kb)
#pragma unroll
        for (int qb = 0; qb < 2; ++qb) {
          f32x4 p;
#pragma unroll
          for (int r = 0; r < 4; ++r) {
            float val = fast_exp2(fmaf(s[kb][qb][r], scale2, ioff[qb][kb] + rc[r]));
            p[r] = (r <= lim[qb][kb]) ? val : 0.f;
          }
          accLp[qb] += p[0] + p[1] + p[2] + p[3];
          *(short4v*)&Ps[wave][pwoff[qb][kb]] = cvt4(p);
        }
    } else {
#pragma unroll
      for (int kb = 0; kb < 2; ++kb)
#pragma unroll
        for (int qb = 0; qb < 2; ++qb) {
          f32x4 p;
#pragma unroll
          for (int r = 0; r < 4; ++r)
            p[r] = fast_exp2(fmaf(s[kb][qb][r], scale2, ioff[qb][kb] + rc[r]));
          accLp[qb] += p[0] + p[1] + p[2] + p[3];
          *(short4v*)&Ps[wave][pwoff[qb][kb]] = cvt4(p);
        }
    }
#pragma unroll
    for (int qb = 0; qb < 2; ++qb)
#pragma unroll
      for (int kb = 0; kb < 2; ++kb) ioff[qb][kb] += s64;

    // P fragments -> carried registers (wave-private Ps; lgkm wait only)
    paA = *(const short8*)&Ps[wave][proff0];
    paB = *(const short8*)&Ps[wave][proff1];

    __syncthreads();  // publishes buf[nxt] + frees buf[cur]
  }

  // drain PV(qt)
#pragma unroll
  for (int i = 0; i < 4; ++i) {
    accO[i][0] = __builtin_amdgcn_mfma_f32_16x16x32_bf16(var[i], paA, accO[i][0], 0, 0, 0);
    accO[i][1] = __builtin_amdgcn_mfma_f32_16x16x32_bf16(var[i], paB, accO[i][1], 0, 0, 0);
  }

  // merge kh halves: kh=1 writes partials to LDS scratch, kh=0 reduces+stores
  __syncthreads();  // K/V buffers dead; reuse as scratch
  float* scr = (qh == 0) ? (float*)&Ks[0][0] : (float*)&Vs[0][0];  // 16 KB each
  float* s0 = scr + lane * 40;  // 160B stride, 16B-aligned
  if (kh) {
#pragma unroll
    for (int i = 0; i < 4; ++i)
#pragma unroll
      for (int qb = 0; qb < 2; ++qb)
        *(f32x4*)&s0[(i * 2 + qb) * 4] = accO[i][qb];
    s0[32] = accLp[0];
    s0[33] = accLp[1];
  }
  __syncthreads();
  if (!kh) {
#pragma unroll
    for (int i = 0; i < 4; ++i)
#pragma unroll
      for (int qb = 0; qb < 2; ++qb) {
        f32x4 t = *(const f32x4*)&s0[(i * 2 + qb) * 4];
#pragma unroll
        for (int r = 0; r < 4; ++r) accO[i][qb][r] += t[r];
      }
    accLp[0] += s0[32];
    accLp[1] += s0[33];
    const int b = bh >> 4;
#pragma unroll
    for (int qb = 0; qb < 2; ++qb) {
      float lsum = accLp[qb];
      lsum += __shfl_xor(lsum, 16);
      lsum += __shfl_xor(lsum, 32);
      const float inv = 1.0f / lsum;
      const int qrow = (qb == 0) ? qrowA : qrowB;
      short* ob = o + ((((size_t)b * SEQ + qrow) * NH + h) * DH + 4 * quad);
#pragma unroll
      for (int i = 0; i < 4; ++i) {
        f32x4 t;
#pragma unroll
        for (int r = 0; r < 4; ++r) t[r] = accO[i][qb][r] * inv;
        *(short4v*)&ob[16 * i] = cvt4(t);
      }
    }
  }
}

extern "C" void kernel_launch(void* const* d_in, const int* in_sizes, int n_in,
                              void* d_out, int out_size, void* d_ws, size_t ws_size,
                              hipStream_t stream) {
  const float* x = (const float*)d_in[0];      // [2,2048,1024]
  const float* w_in = (const float*)d_in[1];   // [1024,3072]
  const float* b_in = (const float*)d_in[2];   // [3072]
  const float* w_out = (const float*)d_in[3];  // [1024,1024]
  const float* b_out = (const float*)d_in[4];  // [1024]
  float* out = (float*)d_out;

  char* ws = (char*)d_ws;
  short* xb = (short*)(ws);                     // 8 MB  bf16 x
  short* w_in_t = (short*)(ws + (8u << 20));    // 6 MB  bf16 w_in^T [3072][1024]
  short* w_out_t = (short*)(ws + (14u << 20));  // 2 MB  bf16 w_out^T
  short* qv = (short*)(ws + (16u << 20));       // 8 MB  [B,H,L,dh]
  short* kv = (short*)(ws + (24u << 20));       // 8 MB  [B,H,L,dh]
  short* vv = (short*)(ws + (32u << 20));       // 8 MB  [B,H,dh,L] (transposed)
  short* ao = (short*)(ws + (40u << 20));       // 8 MB  attn out [B,L,D] bf16

  k_prep<<<8192, 256, 0, stream>>>(x, xb, w_in, w_in_t, w_out, w_out_t);
  k_gemm<0><<<dim3(24, 32), 256, 0, stream>>>(xb, w_in_t, b_in, nullptr, qv, kv, vv);
  k_attn<<<1024, 256, 0, stream>>>(qv, kv, vv, ao);
  k_gemm<1><<<dim3(8, 32), 256, 0, stream>>>(ao, w_out_t, b_out, out, nullptr, nullptr, nullptr);
}

// Round 9
// 176.258 us; speedup vs baseline: 1.0412x; 1.0412x over previous
//
#include <hip/hip_runtime.h>
#include <stdint.h>
#include <math.h>

#define NH 16
#define DH 64
#define SEQ 2048
#define DMODEL 1024

typedef short short8 __attribute__((ext_vector_type(8)));
typedef short short4v __attribute__((ext_vector_type(4)));
typedef float f32x4 __attribute__((ext_vector_type(4)));
typedef __bf16 bf16x4 __attribute__((ext_vector_type(4)));

__device__ __forceinline__ short f2bf(float f) {
  __bf16 h = (__bf16)f;
  return __builtin_bit_cast(short, h);
}
__device__ __forceinline__ short4v cvt4(f32x4 v) {
  bf16x4 b = __builtin_convertvector(v, bf16x4);
  return __builtin_bit_cast(short4v, b);
}
__device__ __forceinline__ float fast_exp2(float x) {
#if __has_builtin(__builtin_amdgcn_exp2f)
  return __builtin_amdgcn_exp2f(x);
#else
  return exp2f(x);
#endif
}

typedef const __attribute__((address_space(1))) uint32_t* gp_t;
typedef __attribute__((address_space(3))) uint32_t* lp_t;
__device__ __forceinline__ void async16(const short* g, short* l) {
  __builtin_amdgcn_global_load_lds((gp_t)g, (lp_t)l, 16, 0, 0);
}

// ---- fused prep: x fp32->bf16 | w_in^T bf16 | w_out^T bf16 (one launch) ----
__device__ __forceinline__ void transpose_tile(const float* __restrict__ in,
                                               short* __restrict__ out, int R, int C,
                                               int t, int tilesX, int tid) {
  __shared__ float tile[32][33];
  const int tx = tid & 31, ty = tid >> 5;  // 32 x 8
  const int c0 = (t % tilesX) * 32, r0 = (t / tilesX) * 32;
#pragma unroll
  for (int i = 0; i < 4; ++i)
    tile[ty + i * 8][tx] = in[(size_t)(r0 + ty + i * 8) * C + c0 + tx];
  __syncthreads();
#pragma unroll
  for (int i = 0; i < 4; ++i)
    out[(size_t)(c0 + ty + i * 8) * R + r0 + tx] = f2bf(tile[tx][ty + i * 8]);
}

__global__ void k_prep(const float* __restrict__ x, short* __restrict__ xb,
                       const float* __restrict__ w_in, short* __restrict__ w_in_t,
                       const float* __restrict__ w_out, short* __restrict__ w_out_t) {
  const int tid = threadIdx.x;
  const int blk = blockIdx.x;
  if (blk < 4096) {  // x convert
    const int i = blk * 256 + tid;
    f32x4 v = ((const f32x4*)x)[i];
    ((short4v*)xb)[i] = cvt4(v);
  } else if (blk < 4096 + 3072) {  // w_in [1024,3072] -> [3072,1024]
    transpose_tile(w_in, w_in_t, 1024, 3072, blk - 4096, 96, tid);
  } else {  // w_out [1024,1024] -> transpose
    transpose_tile(w_out, w_out_t, 1024, 1024, blk - 7168, 32, tid);
  }
}

// ---------------- GEMM: C[M,N] = A[M,K=1024] * Bt[N,K]^T + bias ------------
// BK=64: 16 K-iters x 32 MFMA. LDS tiles 128x64, XOR-chunk-swizzled so
// global_load_lds (linear, wave-uniform-base) + conflict-free b128 reads.
template <int MODE>
__launch_bounds__(256, 3)
__global__ void k_gemm(const short* __restrict__ A, const short* __restrict__ Bt,
                       const float* __restrict__ bias, float* __restrict__ Cf,
                       short* __restrict__ qo, short* __restrict__ ko,
                       short* __restrict__ vo) {
  constexpr int KD = 1024;
  __shared__ __align__(16) short As[128 * 64];  // 16 KB
  __shared__ __align__(16) short Bs[128 * 64];  // 16 KB
  const int tid = threadIdx.x;
  const int wave = tid >> 6, lane = tid & 63;
  const int quad = lane >> 4, l16 = lane & 15;
  const int wm = wave >> 1, wn = wave & 1;
  const int tM = blockIdx.y * 128, tN = blockIdx.x * 128;

  const short* pA[4];
  const short* pB[4];
  short* lA[4];
  short* lB[4];
#pragma unroll
  for (int t = 0; t < 4; ++t) {
    const int c = t * 256 + tid;
    const int row = c >> 3, gch = (c & 7) ^ (row & 7);
    pA[t] = A + (size_t)(tM + row) * KD + gch * 8;
    pB[t] = Bt + (size_t)(tN + row) * KD + gch * 8;
    lA[t] = &As[c * 8];
    lB[t] = &Bs[c * 8];
  }

  const int sw = l16 & 7;
  const int col0 = (quad ^ sw) << 3;
  const int col1 = col0 ^ 32;

  f32x4 acc[4][4] = {};

  for (int k0 = 0; k0 < KD; k0 += 64) {
    __syncthreads();
#pragma unroll
    for (int t = 0; t < 4; ++t) {
      async16(pA[t] + k0, lA[t]);
      async16(pB[t] + k0, lB[t]);
    }
    __syncthreads();
#pragma unroll
    for (int kh = 0; kh < 2; ++kh) {
      const int col = kh ? col1 : col0;
      short8 af[4], bfr[4];
#pragma unroll
      for (int i = 0; i < 4; ++i)
        af[i] = *(const short8*)&As[(wm * 64 + i * 16 + l16) * 64 + col];
#pragma unroll
      for (int i = 0; i < 4; ++i)
        bfr[i] = *(const short8*)&Bs[(wn * 64 + i * 16 + l16) * 64 + col];
#pragma unroll
      for (int i = 0; i < 4; ++i)
#pragma unroll
        for (int j = 0; j < 4; ++j)
          acc[i][j] = __builtin_amdgcn_mfma_f32_16x16x32_bf16(af[i], bfr[j], acc[i][j], 0, 0, 0);
    }
  }

  const int rbase = tM + wm * 64 + quad * 4;
#pragma unroll
  for (int i = 0; i < 4; ++i) {
#pragma unroll
    for (int j = 0; j < 4; ++j) {
      const int col = tN + wn * 64 + j * 16 + l16;
      const float bi = bias[col];
      if (MODE == 0) {
        const int which = col >> 10;  // uniform per block
        const int h = (col & 1023) >> 6, d = col & 63;
        if (which == 2) {
          const int row0 = rbase + i * 16;
          const int b = row0 >> 11, li0 = row0 & 2047;
          f32x4 t;
#pragma unroll
          for (int rr = 0; rr < 4; ++rr) t[rr] = acc[i][j][rr] + bi;
          *(short4v*)&vo[(((size_t)(b * NH + h)) * DH + d) * SEQ + li0] = cvt4(t);
        } else {
          short* dst = (which == 0) ? qo : ko;
#pragma unroll
          for (int rr = 0; rr < 4; ++rr) {
            const int row = rbase + i * 16 + rr;
            const int b = row >> 11, li = row & 2047;
            dst[(((size_t)(b * NH + h)) * SEQ + li) * DH + d] = f2bf(acc[i][j][rr] + bi);
          }
        }
      } else {
#pragma unroll
        for (int rr = 0; rr < 4; ++rr) {
          const int row = rbase + i * 16 + rr;
          Cf[(size_t)row * DMODEL + col] = acc[i][j][rr] + bi;
        }
      }
    }
  }
}

// -------- flash attention: paired q-panels, uniform 33-unit blocks ----------
// r7 inner structure (LDS-staged K/V, double-buffered, T15 register-carried
// PV one tile behind, setprio) with the ragged-tail fix: each block owns TWO
// q-panels (qtA=31-g, qtB=g) processed sequentially => every block is exactly
// 33 tile-units. Grid 512 = 16 pairs x 32 bh; 2 blocks/CU, uniform 8 waves/CU
// (r7's LPT blocks starved the tail: avg occupancy 22%, last ~8 tiles of the
// long block ran at 4 waves). Prefetch stream is seamless across the panel
// switch: panel A's last iteration stages panel B's tile 0 (ptr redirect),
// parity carries through. Panel A output stores from registers after its
// drain — no LDS interaction with panel B's already-running waves.
__launch_bounds__(256)
__global__ void k_attn(const short* __restrict__ q, const short* __restrict__ k,
                       const short* __restrict__ vt, short* __restrict__ o) {
  __shared__ __align__(16) short Ks[2][64 * 64];  // 2 x 8 KB
  __shared__ __align__(16) short Vs[2][64 * 64];  // 2 x 8 KB, V^T tile [d][key]
  __shared__ __align__(16) short Ps[4][16 * 64];  // per-wave P, swizzled
  const int tid = threadIdx.x;
  const int wave = tid >> 6, lane = tid & 63;
  const int quad = lane >> 4, l16 = lane & 15;
  const int sw = l16 & 7;
  const int bx = blockIdx.x;
  const int g = bx >> 5;           // 0..15
  const int bh = bx & 31;
  const int qtA = 31 - g, qtB = g;  // qtA + qtB + 2 = 33 units, all blocks equal
  const int h = bh & (NH - 1);
  const size_t base = (size_t)bh * SEQ * DH;
  const float LOG2E = 1.44269504088896f;
  const float slope2 = exp2f(-0.5f * (float)(h + 1)) * LOG2E;
  const float scale2 = 0.125f * LOG2E;
  const float FM = 12.0f;  // fixed softmax max; cancels in O/l exactly

  // staging chunks: c = t*256+tid, row=c>>3, ch=(c&7)^(row&7); lds off = c*16B
  const int c0i = tid, c1i = 256 + tid;
  const int r0 = c0i >> 3, ch0 = (c0i & 7) ^ (r0 & 7);
  const int r1 = c1i >> 3, ch1 = (c1i & 7) ^ (r1 & 7);
  const int qk_off0 = r0 * DH + ch0 * 8;
  const int qk_off1 = r1 * DH + ch1 * 8;
  const int v_off0 = r0 * SEQ + ch0 * 8;
  const int v_off1 = r1 * SEQ + ch1 * 8;

  // frag read columns (swizzled)
  const int col0 = ((quad ^ sw) << 3);
  const int col1 = col0 ^ 32;
  int psoff[4];
#pragma unroll
  for (int in = 0; in < 4; ++in)
    psoff[in] = l16 * 64 + (((2 * in + (quad >> 1)) ^ sw) << 3) + (quad & 1) * 4;
  const int qlim4 = wave * 16 + l16 - 4 * quad;  // diag: keep 16*in+r <= qlim4

  short8 ones;
#pragma unroll
  for (int j = 0; j < 8; ++j) ones[j] = (short)0x3F80;  // bf16 1.0

  const float s64 = slope2 * 64.0f;
  float rc[4];
#pragma unroll
  for (int r = 0; r < 4; ++r) rc[r] = slope2 * (float)r;
  const int b = bh >> 4;

  const short* kp = k + base;   // advances 64 rows per tile
  const short* vp = vt + base;  // advances 64 cols per tile

  // stage tile 0 (panel A) into buf 0
  async16(kp + qk_off0, &Ks[0][c0i * 8]);
  async16(kp + qk_off1, &Ks[0][c1i * 8]);
  async16(vp + v_off0, &Vs[0][c0i * 8]);
  async16(vp + v_off1, &Vs[0][c1i * 8]);
  kp += 64 * DH;
  vp += 64;
  __syncthreads();

  // cross-tile carried PV operands (registers survive LDS buffer reuse)
  short8 paA, paB;
  short8 var0[4], var1[4];

  // ======================= PANEL A (qt = qtA) =======================
  {
    const int qrow = qtA * 64 + wave * 16 + l16;
    const short* qp = q + base + (size_t)qrow * DH + quad * 8;
    const short8 qb0 = *(const short8*)qp;
    const short8 qb1 = *(const short8*)(qp + 32);
    float inoff[4];
    const float qoff = -slope2 * (float)qrow - FM + slope2 * (float)(4 * quad);
#pragma unroll
    for (int in = 0; in < 4; ++in) inoff[in] = qoff + slope2 * (float)(16 * in);
    f32x4 accO[4] = {};
    f32x4 accL = {};

    for (int kt = 0; kt <= qtA; ++kt) {
      const int cur = kt & 1, nxt = cur ^ 1;
      if (kt == qtA) { kp = k + base; vp = vt + base; }  // redirect to panel B tile 0
      // always prefetch next item of the 33-tile stream
      async16(kp + qk_off0, &Ks[nxt][c0i * 8]);
      async16(kp + qk_off1, &Ks[nxt][c1i * 8]);
      async16(vp + v_off0, &Vs[nxt][c0i * 8]);
      async16(vp + v_off1, &Vs[nxt][c1i * 8]);
      kp += 64 * DH;
      vp += 64;

      f32x4 s[4];
      __builtin_amdgcn_s_setprio(1);
#pragma unroll
      for (int in = 0; in < 4; ++in) {
        const short8 ka0 = *(const short8*)&Ks[cur][(in * 16 + l16) * 64 + col0];
        const short8 ka1 = *(const short8*)&Ks[cur][(in * 16 + l16) * 64 + col1];
        f32x4 t = {};
        t = __builtin_amdgcn_mfma_f32_16x16x32_bf16(ka0, qb0, t, 0, 0, 0);
        t = __builtin_amdgcn_mfma_f32_16x16x32_bf16(ka1, qb1, t, 0, 0, 0);
        s[in] = t;
      }
      if (kt > 0) {  // PV(kt-1) from carried registers
        accL = __builtin_amdgcn_mfma_f32_16x16x32_bf16(ones, paA, accL, 0, 0, 0);
        accL = __builtin_amdgcn_mfma_f32_16x16x32_bf16(ones, paB, accL, 0, 0, 0);
#pragma unroll
        for (int i = 0; i < 4; ++i) {
          accO[i] = __builtin_amdgcn_mfma_f32_16x16x32_bf16(var0[i], paA, accO[i], 0, 0, 0);
          accO[i] = __builtin_amdgcn_mfma_f32_16x16x32_bf16(var1[i], paB, accO[i], 0, 0, 0);
        }
      }
      __builtin_amdgcn_s_setprio(0);

#pragma unroll
      for (int i = 0; i < 4; ++i) {
        var0[i] = *(const short8*)&Vs[cur][(i * 16 + l16) * 64 + col0];
        var1[i] = *(const short8*)&Vs[cur][(i * 16 + l16) * 64 + col1];
      }

      if (kt == qtA) {  // diagonal
#pragma unroll
        for (int in = 0; in < 4; ++in) {
          f32x4 p;
#pragma unroll
          for (int r = 0; r < 4; ++r) {
            float val = fast_exp2(fmaf(s[in][r], scale2, inoff[in] + rc[r]));
            p[r] = (16 * in + r <= qlim4) ? val : 0.f;
          }
          *(short4v*)&Ps[wave][psoff[in]] = cvt4(p);
        }
      } else {
#pragma unroll
        for (int in = 0; in < 4; ++in) {
          f32x4 p;
#pragma unroll
          for (int r = 0; r < 4; ++r)
            p[r] = fast_exp2(fmaf(s[in][r], scale2, inoff[in] + rc[r]));
          *(short4v*)&Ps[wave][psoff[in]] = cvt4(p);
        }
      }
#pragma unroll
      for (int in = 0; in < 4; ++in) inoff[in] += s64;

      paA = *(const short8*)&Ps[wave][l16 * 64 + col0];
      paB = *(const short8*)&Ps[wave][l16 * 64 + col1];

      __syncthreads();  // publishes buf[nxt] + frees buf[cur]
    }

    // drain PV(qtA) + store panel A (registers/global only — no LDS hazard)
    accL = __builtin_amdgcn_mfma_f32_16x16x32_bf16(ones, paA, accL, 0, 0, 0);
    accL = __builtin_amdgcn_mfma_f32_16x16x32_bf16(ones, paB, accL, 0, 0, 0);
#pragma unroll
    for (int i = 0; i < 4; ++i) {
      accO[i] = __builtin_amdgcn_mfma_f32_16x16x32_bf16(var0[i], paA, accO[i], 0, 0, 0);
      accO[i] = __builtin_amdgcn_mfma_f32_16x16x32_bf16(var1[i], paB, accO[i], 0, 0, 0);
    }
    const float inv = 1.0f / accL[0];
    short* ob = o + ((((size_t)b * SEQ + qrow) * NH + h) * DH + 4 * quad);
#pragma unroll
    for (int i = 0; i < 4; ++i) {
      f32x4 t;
#pragma unroll
      for (int r = 0; r < 4; ++r) t[r] = accO[i][r] * inv;
      *(short4v*)&ob[16 * i] = cvt4(t);
    }
  }

  // ======================= PANEL B (qt = qtB) =======================
  {
    const int qrow = qtB * 64 + wave * 16 + l16;
    const short* qp = q + base + (size_t)qrow * DH + quad * 8;
    const short8 qb0 = *(const short8*)qp;
    const short8 qb1 = *(const short8*)(qp + 32);
    float inoff[4];
    const float qoff = -slope2 * (float)qrow - FM + slope2 * (float)(4 * quad);
#pragma unroll
    for (int in = 0; in < 4; ++in) inoff[in] = qoff + slope2 * (float)(16 * in);
    f32x4 accO[4] = {};
    f32x4 accL = {};
    const int par = (qtA + 1) & 1;  // parity of panel B tile 0 buffer

    for (int kt = 0; kt <= qtB; ++kt) {
      const int cur = (par + kt) & 1, nxt = cur ^ 1;
      if (kt < qtB) {
        async16(kp + qk_off0, &Ks[nxt][c0i * 8]);
        async16(kp + qk_off1, &Ks[nxt][c1i * 8]);
        async16(vp + v_off0, &Vs[nxt][c0i * 8]);
        async16(vp + v_off1, &Vs[nxt][c1i * 8]);
        kp += 64 * DH;
        vp += 64;
      }

      f32x4 s[4];
      __builtin_amdgcn_s_setprio(1);
#pragma unroll
      for (int in = 0; in < 4; ++in) {
        const short8 ka0 = *(const short8*)&Ks[cur][(in * 16 + l16) * 64 + col0];
        const short8 ka1 = *(const short8*)&Ks[cur][(in * 16 + l16) * 64 + col1];
        f32x4 t = {};
        t = __builtin_amdgcn_mfma_f32_16x16x32_bf16(ka0, qb0, t, 0, 0, 0);
        t = __builtin_amdgcn_mfma_f32_16x16x32_bf16(ka1, qb1, t, 0, 0, 0);
        s[in] = t;
      }
      if (kt > 0) {
        accL = __builtin_amdgcn_mfma_f32_16x16x32_bf16(ones, paA, accL, 0, 0, 0);
        accL = __builtin_amdgcn_mfma_f32_16x16x32_bf16(ones, paB, accL, 0, 0, 0);
#pragma unroll
        for (int i = 0; i < 4; ++i) {
          accO[i] = __builtin_amdgcn_mfma_f32_16x16x32_bf16(var0[i], paA, accO[i], 0, 0, 0);
          accO[i] = __builtin_amdgcn_mfma_f32_16x16x32_bf16(var1[i], paB, accO[i], 0, 0, 0);
        }
      }
      __builtin_amdgcn_s_setprio(0);

#pragma unroll
      for (int i = 0; i < 4; ++i) {
        var0[i] = *(const short8*)&Vs[cur][(i * 16 + l16) * 64 + col0];
        var1[i] = *(const short8*)&Vs[cur][(i * 16 + l16) * 64 + col1];
      }

      if (kt == qtB) {  // diagonal
#pragma unroll
        for (int in = 0; in < 4; ++in) {
          f32x4 p;
#pragma unroll
          for (int r = 0; r < 4; ++r) {
            float val = fast_exp2(fmaf(s[in][r], scale2, inoff[in] + rc[r]));
            p[r] = (16 * in + r <= qlim4) ? val : 0.f;
          }
          *(short4v*)&Ps[wave][psoff[in]] = cvt4(p);
        }
      } else {
#pragma unroll
        for (int in = 0; in < 4; ++in) {
          f32x4 p;
#pragma unroll
          for (int r = 0; r < 4; ++r)
            p[r] = fast_exp2(fmaf(s[in][r], scale2, inoff[in] + rc[r]));
          *(short4v*)&Ps[wave][psoff[in]] = cvt4(p);
        }
      }
#pragma unroll
      for (int in = 0; in < 4; ++in) inoff[in] += s64;

      paA = *(const short8*)&Ps[wave][l16 * 64 + col0];
      paB = *(const short8*)&Ps[wave][l16 * 64 + col1];

      __syncthreads();
    }

    // drain PV(qtB) + store panel B
    accL = __builtin_amdgcn_mfma_f32_16x16x32_bf16(ones, paA, accL, 0, 0, 0);
    accL = __builtin_amdgcn_mfma_f32_16x16x32_bf16(ones, paB, accL, 0, 0, 0);
#pragma unroll
    for (int i = 0; i < 4; ++i) {
      accO[i] = __builtin_amdgcn_mfma_f32_16x16x32_bf16(var0[i], paA, accO[i], 0, 0, 0);
      accO[i] = __builtin_amdgcn_mfma_f32_16x16x32_bf16(var1[i], paB, accO[i], 0, 0, 0);
    }
    const float inv = 1.0f / accL[0];
    short* ob = o + ((((size_t)b * SEQ + qrow) * NH + h) * DH + 4 * quad);
#pragma unroll
    for (int i = 0; i < 4; ++i) {
      f32x4 t;
#pragma unroll
      for (int r = 0; r < 4; ++r) t[r] = accO[i][r] * inv;
      *(short4v*)&ob[16 * i] = cvt4(t);
    }
  }
}

extern "C" void kernel_launch(void* const* d_in, const int* in_sizes, int n_in,
                              void* d_out, int out_size, void* d_ws, size_t ws_size,
                              hipStream_t stream) {
  const float* x = (const float*)d_in[0];      // [2,2048,1024]
  const float* w_in = (const float*)d_in[1];   // [1024,3072]
  const float* b_in = (const float*)d_in[2];   // [3072]
  const float* w_out = (const float*)d_in[3];  // [1024,1024]
  const float* b_out = (const float*)d_in[4];  // [1024]
  float* out = (float*)d_out;

  char* ws = (char*)d_ws;
  short* xb = (short*)(ws);                     // 8 MB  bf16 x
  short* w_in_t = (short*)(ws + (8u << 20));    // 6 MB  bf16 w_in^T [3072][1024]
  short* w_out_t = (short*)(ws + (14u << 20));  // 2 MB  bf16 w_out^T
  short* qv = (short*)(ws + (16u << 20));       // 8 MB  [B,H,L,dh]
  short* kv = (short*)(ws + (24u << 20));       // 8 MB  [B,H,L,dh]
  short* vv = (short*)(ws + (32u << 20));       // 8 MB  [B,H,dh,L] (transposed)
  short* ao = (short*)(ws + (40u << 20));       // 8 MB  attn out [B,L,D] bf16

  k_prep<<<8192, 256, 0, stream>>>(x, xb, w_in, w_in_t, w_out, w_out_t);
  k_gemm<0><<<dim3(24, 32), 256, 0, stream>>>(xb, w_in_t, b_in, nullptr, qv, kv, vv);
  k_attn<<<512, 256, 0, stream>>>(qv, kv, vv, ao);
  k_gemm<1><<<dim3(8, 32), 256, 0, stream>>>(ao, w_out_t, b_out, out, nullptr, nullptr, nullptr);
}

// Round 10
// 170.723 us; speedup vs baseline: 1.0749x; 1.0324x over previous
//
#include <hip/hip_runtime.h>
#include <stdint.h>
#include <math.h>

#define NH 16
#define DH 64
#define SEQ 2048
#define DMODEL 1024

typedef short short8 __attribute__((ext_vector_type(8)));
typedef short short4v __attribute__((ext_vector_type(4)));
typedef float f32x4 __attribute__((ext_vector_type(4)));
typedef __bf16 bf16x4 __attribute__((ext_vector_type(4)));

__device__ __forceinline__ short f2bf(float f) {
  __bf16 h = (__bf16)f;
  return __builtin_bit_cast(short, h);
}
__device__ __forceinline__ short4v cvt4(f32x4 v) {
  bf16x4 b = __builtin_convertvector(v, bf16x4);
  return __builtin_bit_cast(short4v, b);
}
__device__ __forceinline__ float fast_exp2(float x) {
#if __has_builtin(__builtin_amdgcn_exp2f)
  return __builtin_amdgcn_exp2f(x);
#else
  return exp2f(x);
#endif
}

typedef const __attribute__((address_space(1))) uint32_t* gp_t;
typedef __attribute__((address_space(3))) uint32_t* lp_t;
__device__ __forceinline__ void async16(const short* g, short* l) {
  __builtin_amdgcn_global_load_lds((gp_t)g, (lp_t)l, 16, 0, 0);
}

// ---- fused prep: x fp32->bf16 | w_in^T bf16 | w_out^T bf16 (one launch) ----
__device__ __forceinline__ void transpose_tile(const float* __restrict__ in,
                                               short* __restrict__ out, int R, int C,
                                               int t, int tilesX, int tid) {
  __shared__ float tile[32][33];
  const int tx = tid & 31, ty = tid >> 5;  // 32 x 8
  const int c0 = (t % tilesX) * 32, r0 = (t / tilesX) * 32;
#pragma unroll
  for (int i = 0; i < 4; ++i)
    tile[ty + i * 8][tx] = in[(size_t)(r0 + ty + i * 8) * C + c0 + tx];
  __syncthreads();
#pragma unroll
  for (int i = 0; i < 4; ++i)
    out[(size_t)(c0 + ty + i * 8) * R + r0 + tx] = f2bf(tile[tx][ty + i * 8]);
}

__global__ void k_prep(const float* __restrict__ x, short* __restrict__ xb,
                       const float* __restrict__ w_in, short* __restrict__ w_in_t,
                       const float* __restrict__ w_out, short* __restrict__ w_out_t) {
  const int tid = threadIdx.x;
  const int blk = blockIdx.x;
  if (blk < 4096) {  // x convert
    const int i = blk * 256 + tid;
    f32x4 v = ((const f32x4*)x)[i];
    ((short4v*)xb)[i] = cvt4(v);
  } else if (blk < 4096 + 3072) {  // w_in [1024,3072] -> [3072,1024]
    transpose_tile(w_in, w_in_t, 1024, 3072, blk - 4096, 96, tid);
  } else {  // w_out [1024,1024] -> transpose
    transpose_tile(w_out, w_out_t, 1024, 1024, blk - 7168, 32, tid);
  }
}

// ---------------- GEMM (QKV): C[M,N] = A[M,K=1024] * Bt[N,K]^T + bias ------
// BK=64: 16 K-iters x 32 MFMA. LDS tiles 128x64, XOR-chunk-swizzled so
// global_load_lds (linear, wave-uniform-base) + conflict-free b128 reads.
__launch_bounds__(256, 3)
__global__ void k_gemm(const short* __restrict__ A, const short* __restrict__ Bt,
                       const float* __restrict__ bias,
                       short* __restrict__ qo, short* __restrict__ ko,
                       short* __restrict__ vo) {
  constexpr int KD = 1024;
  __shared__ __align__(16) short As[128 * 64];  // 16 KB
  __shared__ __align__(16) short Bs[128 * 64];  // 16 KB
  const int tid = threadIdx.x;
  const int wave = tid >> 6, lane = tid & 63;
  const int quad = lane >> 4, l16 = lane & 15;
  const int wm = wave >> 1, wn = wave & 1;
  const int tM = blockIdx.y * 128, tN = blockIdx.x * 128;

  const short* pA[4];
  const short* pB[4];
  short* lA[4];
  short* lB[4];
#pragma unroll
  for (int t = 0; t < 4; ++t) {
    const int c = t * 256 + tid;
    const int row = c >> 3, gch = (c & 7) ^ (row & 7);
    pA[t] = A + (size_t)(tM + row) * KD + gch * 8;
    pB[t] = Bt + (size_t)(tN + row) * KD + gch * 8;
    lA[t] = &As[c * 8];
    lB[t] = &Bs[c * 8];
  }

  const int sw = l16 & 7;
  const int col0 = (quad ^ sw) << 3;
  const int col1 = col0 ^ 32;

  f32x4 acc[4][4] = {};

  for (int k0 = 0; k0 < KD; k0 += 64) {
    __syncthreads();
#pragma unroll
    for (int t = 0; t < 4; ++t) {
      async16(pA[t] + k0, lA[t]);
      async16(pB[t] + k0, lB[t]);
    }
    __syncthreads();
#pragma unroll
    for (int kh = 0; kh < 2; ++kh) {
      const int col = kh ? col1 : col0;
      short8 af[4], bfr[4];
#pragma unroll
      for (int i = 0; i < 4; ++i)
        af[i] = *(const short8*)&As[(wm * 64 + i * 16 + l16) * 64 + col];
#pragma unroll
      for (int i = 0; i < 4; ++i)
        bfr[i] = *(const short8*)&Bs[(wn * 64 + i * 16 + l16) * 64 + col];
#pragma unroll
      for (int i = 0; i < 4; ++i)
#pragma unroll
        for (int j = 0; j < 4; ++j)
          acc[i][j] = __builtin_amdgcn_mfma_f32_16x16x32_bf16(af[i], bfr[j], acc[i][j], 0, 0, 0);
    }
  }

  const int rbase = tM + wm * 64 + quad * 4;
#pragma unroll
  for (int i = 0; i < 4; ++i) {
#pragma unroll
    for (int j = 0; j < 4; ++j) {
      const int col = tN + wn * 64 + j * 16 + l16;
      const float bi = bias[col];
      const int which = col >> 10;  // uniform per block
      const int h = (col & 1023) >> 6, d = col & 63;
      if (which == 2) {
        const int row0 = rbase + i * 16;
        const int b = row0 >> 11, li0 = row0 & 2047;
        f32x4 t;
#pragma unroll
        for (int rr = 0; rr < 4; ++rr) t[rr] = acc[i][j][rr] + bi;
        *(short4v*)&vo[(((size_t)(b * NH + h)) * DH + d) * SEQ + li0] = cvt4(t);
      } else {
        short* dst = (which == 0) ? qo : ko;
#pragma unroll
        for (int rr = 0; rr < 4; ++rr) {
          const int row = rbase + i * 16 + rr;
          const int b = row >> 11, li = row & 2047;
          dst[(((size_t)(b * NH + h)) * SEQ + li) * DH + d] = f2bf(acc[i][j][rr] + bi);
        }
      }
    }
  }
}

// ---------- GEMM2 (out-proj): BM=128 x BN=64 -> 512 blocks = 2/CU ----------
// Same verified staging/swizzle algebra as k_gemm, restricted to a 64-col
// B tile (2 staging chunks, acc[4][2], waves 2Mx2N each 64x32 output).
// Fixes gemm1's 1-block/CU starvation (256 blocks at 128x128 = 4 waves/CU).
__launch_bounds__(256)
__global__ void k_gemm2(const short* __restrict__ A, const short* __restrict__ Bt,
                        const float* __restrict__ bias, float* __restrict__ Cf) {
  constexpr int KD = 1024;
  __shared__ __align__(16) short As[128 * 64];  // 16 KB
  __shared__ __align__(16) short Bs[64 * 64];   // 8 KB
  const int tid = threadIdx.x;
  const int wave = tid >> 6, lane = tid & 63;
  const int quad = lane >> 4, l16 = lane & 15;
  const int wm = wave >> 1, wn = wave & 1;
  const int tM = blockIdx.y * 128, tN = blockIdx.x * 64;

  const short* pA[4];
  short* lA[4];
#pragma unroll
  for (int t = 0; t < 4; ++t) {
    const int c = t * 256 + tid;
    const int row = c >> 3, gch = (c & 7) ^ (row & 7);
    pA[t] = A + (size_t)(tM + row) * KD + gch * 8;
    lA[t] = &As[c * 8];
  }
  const short* pB[2];
  short* lB[2];
#pragma unroll
  for (int t = 0; t < 2; ++t) {
    const int c = t * 256 + tid;
    const int row = c >> 3, gch = (c & 7) ^ (row & 7);
    pB[t] = Bt + (size_t)(tN + row) * KD + gch * 8;
    lB[t] = &Bs[c * 8];
  }

  const int sw = l16 & 7;
  const int col0 = (quad ^ sw) << 3;
  const int col1 = col0 ^ 32;

  f32x4 acc[4][2] = {};

  for (int k0 = 0; k0 < KD; k0 += 64) {
    __syncthreads();
#pragma unroll
    for (int t = 0; t < 4; ++t) async16(pA[t] + k0, lA[t]);
#pragma unroll
    for (int t = 0; t < 2; ++t) async16(pB[t] + k0, lB[t]);
    __syncthreads();
#pragma unroll
    for (int kh = 0; kh < 2; ++kh) {
      const int col = kh ? col1 : col0;
      short8 af[4], bfr[2];
#pragma unroll
      for (int i = 0; i < 4; ++i)
        af[i] = *(const short8*)&As[(wm * 64 + i * 16 + l16) * 64 + col];
#pragma unroll
      for (int j = 0; j < 2; ++j)
        bfr[j] = *(const short8*)&Bs[(wn * 32 + j * 16 + l16) * 64 + col];
#pragma unroll
      for (int i = 0; i < 4; ++i)
#pragma unroll
        for (int j = 0; j < 2; ++j)
          acc[i][j] = __builtin_amdgcn_mfma_f32_16x16x32_bf16(af[i], bfr[j], acc[i][j], 0, 0, 0);
    }
  }

  const int rbase = tM + wm * 64 + quad * 4;
#pragma unroll
  for (int i = 0; i < 4; ++i) {
#pragma unroll
    for (int j = 0; j < 2; ++j) {
      const int col = tN + wn * 32 + j * 16 + l16;
      const float bi = bias[col];
#pragma unroll
      for (int rr = 0; rr < 4; ++rr) {
        const int row = rbase + i * 16 + rr;
        Cf[(size_t)row * DMODEL + col] = acc[i][j][rr] + bi;
      }
    }
  }
}

// -------- flash attention: LDS-staged K/V + cross-tile software pipeline ----
// r7 kernel VERBATIM (measured: attn 42.9 us, total 167.4). Staged,
// double-buffered, balanced qt remap, setprio, T15 register-carried PV one
// tile behind. Plain __launch_bounds__(256): the (256,4) cap spilled (r6).
__launch_bounds__(256)
__global__ void k_attn(const short* __restrict__ q, const short* __restrict__ k,
                       const short* __restrict__ vt, short* __restrict__ o) {
  __shared__ __align__(16) short Ks[2][64 * 64];  // 2 x 8 KB
  __shared__ __align__(16) short Vs[2][64 * 64];  // 2 x 8 KB, V^T tile [d][key]
  __shared__ __align__(16) short Ps[4][16 * 64];  // per-wave P [q][key], swizzled
  const int tid = threadIdx.x;
  const int wave = tid >> 6, lane = tid & 63;
  const int quad = lane >> 4, l16 = lane & 15;
  const int sw = l16 & 7;
  const int bx = blockIdx.x;
  const int g = bx >> 5, g0 = g & 7, sel = g >> 3;
  const int qt = (sel == 0) ? 31 - g0 : (sel == 1) ? g0 : (sel == 2) ? 23 - g0 : 8 + g0;
  const int bh = bx & 31;
  const int h = bh & (NH - 1);
  const size_t base = (size_t)bh * SEQ * DH;
  const float LOG2E = 1.44269504088896f;
  const float slope2 = exp2f(-0.5f * (float)(h + 1)) * LOG2E;
  const float scale2 = 0.125f * LOG2E;
  const float FM = 12.0f;  // fixed softmax max; cancels in O/l exactly

  // staging chunks: c = t*256+tid, row=c>>3, ch=(c&7)^(row&7); lds off = c*16B
  const int c0i = tid, c1i = 256 + tid;
  const int r0 = c0i >> 3, ch0 = (c0i & 7) ^ (r0 & 7);
  const int r1 = c1i >> 3, ch1 = (c1i & 7) ^ (r1 & 7);
  const int qk_off0 = r0 * DH + ch0 * 8;
  const int qk_off1 = r1 * DH + ch1 * 8;
  const int v_off0 = r0 * SEQ + ch0 * 8;
  const int v_off1 = r1 * SEQ + ch1 * 8;

  // frag read columns (swizzled)
  const int col0 = ((quad ^ sw) << 3);
  const int col1 = col0 ^ 32;
  int psoff[4];
#pragma unroll
  for (int in = 0; in < 4; ++in)
    psoff[in] = l16 * 64 + (((2 * in + (quad >> 1)) ^ sw) << 3) + (quad & 1) * 4;
  const int qlim4 = wave * 16 + l16 - 4 * quad;  // diag: keep 16*in+r <= qlim4

  const int q0 = qt * 64;
  const int qrow = q0 + wave * 16 + l16;  // each lane owns ONE q-row
  // Q fragment: direct global one-time load (B-operand layout)
  const short* qp = q + base + (size_t)qrow * DH + quad * 8;
  const short8 qb0 = *(const short8*)qp;
  const short8 qb1 = *(const short8*)(qp + 32);

  short8 ones;
#pragma unroll
  for (int j = 0; j < 8; ++j) ones[j] = (short)0x3F80;  // bf16 1.0

  f32x4 accO[4] = {};
  f32x4 accL = {};
  const float qoff = -slope2 * (float)qrow - FM + slope2 * (float)(4 * quad);
  float inoff[4];
#pragma unroll
  for (int in = 0; in < 4; ++in)
    inoff[in] = qoff + slope2 * (float)(16 * in);
  const float s64 = slope2 * 64.0f;
  float rc[4];
#pragma unroll
  for (int r = 0; r < 4; ++r) rc[r] = slope2 * (float)r;

  const short* kp = k + base;   // advances 64 rows per tile
  const short* vp = vt + base;  // advances 64 cols per tile

  // stage tile 0 into buf 0
  async16(kp + qk_off0, &Ks[0][c0i * 8]);
  async16(kp + qk_off1, &Ks[0][c1i * 8]);
  async16(vp + v_off0, &Vs[0][c0i * 8]);
  async16(vp + v_off1, &Vs[0][c1i * 8]);
  kp += 64 * DH;
  vp += 64;
  __syncthreads();

  // cross-tile carried PV operands (registers survive LDS buffer reuse)
  short8 paA, paB;
  short8 var0[4], var1[4];

  for (int kt = 0; kt <= qt; ++kt) {
    const int cur = kt & 1, nxt = cur ^ 1;
    if (kt < qt) {  // prefetch kt+1 BEFORE compute; barrier drains it after
      async16(kp + qk_off0, &Ks[nxt][c0i * 8]);
      async16(kp + qk_off1, &Ks[nxt][c1i * 8]);
      async16(vp + v_off0, &Vs[nxt][c0i * 8]);
      async16(vp + v_off1, &Vs[nxt][c1i * 8]);
      kp += 64 * DH;
      vp += 64;
    }

    // S^T = K Q^T : lane holds keys 16*in+4*quad+r for q-row l16
    f32x4 s[4];
    __builtin_amdgcn_s_setprio(1);
#pragma unroll
    for (int in = 0; in < 4; ++in) {
      const short8 ka0 = *(const short8*)&Ks[cur][(in * 16 + l16) * 64 + col0];
      const short8 ka1 = *(const short8*)&Ks[cur][(in * 16 + l16) * 64 + col1];
      f32x4 t = {};
      t = __builtin_amdgcn_mfma_f32_16x16x32_bf16(ka0, qb0, t, 0, 0, 0);
      t = __builtin_amdgcn_mfma_f32_16x16x32_bf16(ka1, qb1, t, 0, 0, 0);
      s[in] = t;
    }

    // PV(kt-1): fully independent of the QK->exp chain above — fills the
    // ds_read + exp latency shadows. Operands carried in registers.
    if (kt > 0) {
      accL = __builtin_amdgcn_mfma_f32_16x16x32_bf16(ones, paA, accL, 0, 0, 0);
      accL = __builtin_amdgcn_mfma_f32_16x16x32_bf16(ones, paB, accL, 0, 0, 0);
#pragma unroll
      for (int i = 0; i < 4; ++i) {
        accO[i] = __builtin_amdgcn_mfma_f32_16x16x32_bf16(var0[i], paA, accO[i], 0, 0, 0);
        accO[i] = __builtin_amdgcn_mfma_f32_16x16x32_bf16(var1[i], paB, accO[i], 0, 0, 0);
      }
    }
    __builtin_amdgcn_s_setprio(0);

    // V(kt) fragments -> registers (consumed next iteration)
#pragma unroll
    for (int i = 0; i < 4; ++i) {
      var0[i] = *(const short8*)&Vs[cur][(i * 16 + l16) * 64 + col0];
      var1[i] = *(const short8*)&Vs[cur][(i * 16 + l16) * 64 + col1];
    }

    if (kt == qt) {  // diagonal: causal mask
#pragma unroll
      for (int in = 0; in < 4; ++in) {
        f32x4 p;
#pragma unroll
        for (int r = 0; r < 4; ++r) {
          float val = fast_exp2(fmaf(s[in][r], scale2, inoff[in] + rc[r]));
          p[r] = (16 * in + r <= qlim4) ? val : 0.f;
        }
        *(short4v*)&Ps[wave][psoff[in]] = cvt4(p);
      }
    } else {
#pragma unroll
      for (int in = 0; in < 4; ++in) {
        f32x4 p;
#pragma unroll
        for (int r = 0; r < 4; ++r)
          p[r] = fast_exp2(fmaf(s[in][r], scale2, inoff[in] + rc[r]));
        *(short4v*)&Ps[wave][psoff[in]] = cvt4(p);
      }
    }
#pragma unroll
    for (int in = 0; in < 4; ++in) inoff[in] += s64;

    // P(kt) fragments -> registers (Ps is wave-private; lgkm wait only)
    paA = *(const short8*)&Ps[wave][l16 * 64 + col0];
    paB = *(const short8*)&Ps[wave][l16 * 64 + col1];

    __syncthreads();  // publishes buf[nxt] (prefetch) + frees buf[cur]
  }

  // epilogue: drain PV(qt)
  __builtin_amdgcn_s_setprio(1);
  accL = __builtin_amdgcn_mfma_f32_16x16x32_bf16(ones, paA, accL, 0, 0, 0);
  accL = __builtin_amdgcn_mfma_f32_16x16x32_bf16(ones, paB, accL, 0, 0, 0);
#pragma unroll
  for (int i = 0; i < 4; ++i) {
    accO[i] = __builtin_amdgcn_mfma_f32_16x16x32_bf16(var0[i], paA, accO[i], 0, 0, 0);
    accO[i] = __builtin_amdgcn_mfma_f32_16x16x32_bf16(var1[i], paB, accO[i], 0, 0, 0);
  }
  __builtin_amdgcn_s_setprio(0);

  const float inv = 1.0f / accL[0];
  const int b = bh >> 4;
  short* ob = o + ((((size_t)b * SEQ + qrow) * NH + h) * DH + 4 * quad);
#pragma unroll
  for (int i = 0; i < 4; ++i) {
    f32x4 t;
#pragma unroll
    for (int r = 0; r < 4; ++r) t[r] = accO[i][r] * inv;
    *(short4v*)&ob[16 * i] = cvt4(t);
  }
}

extern "C" void kernel_launch(void* const* d_in, const int* in_sizes, int n_in,
                              void* d_out, int out_size, void* d_ws, size_t ws_size,
                              hipStream_t stream) {
  const float* x = (const float*)d_in[0];      // [2,2048,1024]
  const float* w_in = (const float*)d_in[1];   // [1024,3072]
  const float* b_in = (const float*)d_in[2];   // [3072]
  const float* w_out = (const float*)d_in[3];  // [1024,1024]
  const float* b_out = (const float*)d_in[4];  // [1024]
  float* out = (float*)d_out;

  char* ws = (char*)d_ws;
  short* xb = (short*)(ws);                     // 8 MB  bf16 x
  short* w_in_t = (short*)(ws + (8u << 20));    // 6 MB  bf16 w_in^T [3072][1024]
  short* w_out_t = (short*)(ws + (14u << 20));  // 2 MB  bf16 w_out^T
  short* qv = (short*)(ws + (16u << 20));       // 8 MB  [B,H,L,dh]
  short* kv = (short*)(ws + (24u << 20));       // 8 MB  [B,H,L,dh]
  short* vv = (short*)(ws + (32u << 20));       // 8 MB  [B,H,dh,L] (transposed)
  short* ao = (short*)(ws + (40u << 20));       // 8 MB  attn out [B,L,D] bf16

  k_prep<<<8192, 256, 0, stream>>>(x, xb, w_in, w_in_t, w_out, w_out_t);
  k_gemm<<<dim3(24, 32), 256, 0, stream>>>(xb, w_in_t, b_in, qv, kv, vv);
  k_attn<<<1024, 256, 0, stream>>>(qv, kv, vv, ao);
  k_gemm2<<<dim3(16, 32), 256, 0, stream>>>(ao, w_out_t, b_out, out);
}